// Round 1
// baseline (25493.700 us; speedup 1.0000x reference)
//
#include <hip/hip_runtime.h>
#include <math.h>

// ---------------------------------------------------------------------------
// VRNN on MI355X.
// Strategy:
//   * Batched pre-pass:  PX = phi_x(x) for all T;  PRE_ENC = PX@enc_w1[:512]+b1
//   * Persistent 64-WG scan kernel (4 grid barriers / step) computes ONLY the
//     recurrence-critical chain, storing h_prev[t] (bf16) and z/em/es to d_out.
//   * Batched post-pass: prior chain (+kld), pz recompute, decoder chain.
// All GEMMs: bf16 MFMA 16x16x32, fp32 accum, weights pre-transposed to [N][K].
// ---------------------------------------------------------------------------

#define NWG 64
#define TT 200
#define BB 256
#define HD 512
#define TB (TT*BB)   // 51200

typedef unsigned short u16;
typedef __attribute__((ext_vector_type(8))) short bf16x8;
typedef __attribute__((ext_vector_type(4))) float f32x4;

// output layout (fp32, concatenated flat): z, logits, em, es, pm, ps, kld
constexpr size_t OFF_Z      = 0;
constexpr size_t OFF_LOGITS = 3276800;
constexpr size_t OFF_EM     = 16384000;
constexpr size_t OFF_ES     = 19660800;
constexpr size_t OFF_PM     = 22937600;
constexpr size_t OFF_PS     = 26214400;
constexpr size_t OFF_KLD    = 29491200;

__device__ __forceinline__ u16 f2bf(float f) {
  union { float f; unsigned u; } v; v.f = f;
  return (u16)((v.u + 0x7fffu + ((v.u >> 16) & 1u)) >> 16);  // RNE
}
__device__ __forceinline__ float bf2f(u16 b) {
  union { unsigned u; float f; } v; v.u = ((unsigned)b) << 16; return v.f;
}
__device__ __forceinline__ float sp_(float x) { return (x > 15.f) ? x : log1pf(expf(x)); }
__device__ __forceinline__ float sigm_(float x) { return 1.f / (1.f + expf(-x)); }

#define MFMA(a,b,c) __builtin_amdgcn_mfma_f32_16x16x32_bf16((a),(b),(c),0,0,0)

// ---------------------------------------------------------------------------
// weight cast+transpose: dst[c*R + r] = bf16(src[r*C + c])   (dst is [C][R])
// ---------------------------------------------------------------------------
#define NSEG 18
struct CastSeg { const float* src; u16* dst; int R; int C; };
struct CastArgs { CastSeg seg[NSEG]; };

__global__ __launch_bounds__(256) void cast_all(CastArgs a) {
  int idx = blockIdx.x * 256 + threadIdx.x;
  #pragma unroll 1
  for (int s = 0; s < NSEG; s++) {
    const int R = a.seg[s].R, C = a.seg[s].C;
    const int sz = R * C;
    if (idx < sz) {
      const int r = idx / C, c = idx - r * C;
      a.seg[s].dst[(size_t)c * R + r] = f2bf(a.seg[s].src[idx]);
      return;
    }
    idx -= sz;
  }
}

__global__ __launch_bounds__(256) void init_k(float* h_cur, u16* H0, unsigned* sync) {
  const int i = blockIdx.x * 256 + threadIdx.x;
  if (i < BB * HD) { h_cur[i] = 0.f; H0[i] = 0; }
  if (i < 2052) sync[i] = 0u;
}

// ---------------------------------------------------------------------------
// generic batched GEMM:  out = act( A1@Bt1^T [+ A2@Bt2^T] + bias )
// A1: [TB][K1] (bf16, or fp32 if a1f32), Bt: [N][K] bf16 (pre-transposed).
// WG = 64x64 tile, wave v -> rows +16v. M fixed = TB.
// ---------------------------------------------------------------------------
struct GB {
  const void* A1; int lda1, K1, a1f32;
  const u16* Bt1;
  const u16* A2; int lda2, K2;
  const u16* Bt2;
  const float* bias;
  u16* outB; float* outF; int ldc;
  int tilesN; int act;   // act: 0 none, 1 relu
};

__device__ __forceinline__ bf16x8 load_a8(const void* A, int f32, size_t row, int lda, int k) {
  if (!f32) return *(const bf16x8*)((const u16*)A + row * (size_t)lda + k);
  const float* p = (const float*)A + row * (size_t)lda + k;
  f32x4 x0 = *(const f32x4*)p;
  f32x4 x1 = *(const f32x4*)(p + 4);
  bf16x8 r;
  r[0]=(short)f2bf(x0[0]); r[1]=(short)f2bf(x0[1]); r[2]=(short)f2bf(x0[2]); r[3]=(short)f2bf(x0[3]);
  r[4]=(short)f2bf(x1[0]); r[5]=(short)f2bf(x1[1]); r[6]=(short)f2bf(x1[2]); r[7]=(short)f2bf(x1[3]);
  return r;
}

__global__ __launch_bounds__(256) void gemm_bt(GB g) {
  const int tn = blockIdx.x % g.tilesN, tm = blockIdx.x / g.tilesN;
  const int m0 = tm * 64, n0 = tn * 64;
  const int v = threadIdx.x >> 6, l = threadIdx.x & 63, lm = l & 15, q = l >> 4;
  const size_t rowA = m0 + v * 16 + lm;
  f32x4 acc[4] = {};
  for (int k0 = 0; k0 < g.K1; k0 += 32) {
    bf16x8 a = load_a8(g.A1, g.a1f32, rowA, g.lda1, k0 + q * 8);
    #pragma unroll
    for (int c = 0; c < 4; c++) {
      bf16x8 b = *(const bf16x8*)(g.Bt1 + (size_t)(n0 + c * 16 + lm) * g.K1 + k0 + q * 8);
      acc[c] = MFMA(a, b, acc[c]);
    }
  }
  if (g.A2) {
    for (int k0 = 0; k0 < g.K2; k0 += 32) {
      bf16x8 a = *(const bf16x8*)(g.A2 + rowA * (size_t)g.lda2 + k0 + q * 8);
      #pragma unroll
      for (int c = 0; c < 4; c++) {
        bf16x8 b = *(const bf16x8*)(g.Bt2 + (size_t)(n0 + c * 16 + lm) * g.K2 + k0 + q * 8);
        acc[c] = MFMA(a, b, acc[c]);
      }
    }
  }
  #pragma unroll
  for (int c = 0; c < 4; c++) {
    const int col = n0 + c * 16 + lm;
    const float bs = g.bias ? g.bias[col] : 0.f;
    #pragma unroll
    for (int r = 0; r < 4; r++) {
      const size_t row = (size_t)m0 + v * 16 + q * 4 + r;
      float x = acc[c][r] + bs;
      if (g.act == 1) x = fmaxf(x, 0.f);
      if (g.outB) g.outB[row * g.ldc + col] = f2bf(x);
      if (g.outF) g.outF[row * g.ldc + col] = x;
    }
  }
}

// ---------------------------------------------------------------------------
// prior mean/std heads + kld, fused.  PR:[TB][512] bf16, pms_t:[128][512]
// rows 0..63 = prior_mean cols, 64..127 = prior_std cols.
// ---------------------------------------------------------------------------
__global__ __launch_bounds__(256) void pms_kld(const u16* PR, const u16* pms_t,
                                               const float* pmb, const float* psb,
                                               float* out) {
  const int m0 = blockIdx.x * 64;
  const int v = threadIdx.x >> 6, l = threadIdx.x & 63, lm = l & 15, q = l >> 4;
  const size_t rowA = m0 + v * 16 + lm;
  f32x4 acc[8] = {};
  for (int k0 = 0; k0 < 512; k0 += 32) {
    bf16x8 a = *(const bf16x8*)(PR + rowA * 512 + k0 + q * 8);
    #pragma unroll
    for (int c = 0; c < 8; c++) {
      bf16x8 b = *(const bf16x8*)(pms_t + (size_t)(c * 16 + lm) * 512 + k0 + q * 8);
      acc[c] = MFMA(a, b, acc[c]);
    }
  }
  #pragma unroll
  for (int c = 0; c < 4; c++) {
    const int colz = c * 16 + lm;
    #pragma unroll
    for (int r = 0; r < 4; r++) {
      const size_t row = (size_t)m0 + v * 16 + q * 4 + r;
      const float pm = acc[c][r] + pmb[colz];
      const float ps = sp_(acc[c + 4][r] + psb[colz]);
      const size_t oi = row * 64 + colz;
      const float em = out[OFF_EM + oi], es = out[OFF_ES + oi];
      const float d = em - pm;
      const float kld = 0.5f * (2.f * logf(ps) - 2.f * logf(es)
                                + (es * es + d * d) / (ps * ps) - 1.f);
      out[OFF_PM + oi] = pm;
      out[OFF_PS + oi] = ps;
      out[OFF_KLD + oi] = kld;
    }
  }
}

// ---------------------------------------------------------------------------
// persistent scan kernel
// ---------------------------------------------------------------------------
struct SC {
  const u16 *pre_enc, *px;
  u16 *H; float *h_cur;
  u16 *A_buf, *E_buf, *PZ_buf;
  float *GH, *GXPX;
  const u16 *enc_w1_h_t, *enc_w2_t, *ems_t, *phi_z_t, *gru_hh_t, *gru_ih_pz_t, *gru_ih_px_t;
  const float *enc_b2, *enc_mean_b, *enc_std_b, *phi_z_b, *gru_b_ih, *gru_b_hh;
  const float *eps;
  float *out;
  unsigned *flags, *gen;
};

// two-level barrier: each WG stores its ticket to its own flag (128B apart);
// WG0 polls all 64 flags with one vector load, then bumps gen; all spin on gen.
__device__ __forceinline__ void gridbar(unsigned* flags, unsigned* gen, unsigned ticket) {
  __syncthreads();
  if (threadIdx.x == 0) {
    __threadfence();   // release: push our writes to device scope
    __hip_atomic_store(&flags[(size_t)blockIdx.x * 32], ticket,
                       __ATOMIC_RELAXED, __HIP_MEMORY_SCOPE_AGENT);
  }
  if (blockIdx.x == 0) {
    if (threadIdx.x < NWG) {
      while (__hip_atomic_load(&flags[(size_t)threadIdx.x * 32],
                               __ATOMIC_RELAXED, __HIP_MEMORY_SCOPE_AGENT) < ticket) {}
    }
    __syncthreads();
    if (threadIdx.x == 0) {
      __threadfence();
      __hip_atomic_store(gen, ticket, __ATOMIC_RELEASE, __HIP_MEMORY_SCOPE_AGENT);
    }
  }
  if (threadIdx.x == 0) {
    while (__hip_atomic_load(gen, __ATOMIC_RELAXED, __HIP_MEMORY_SCOPE_AGENT) < ticket) {
      __builtin_amdgcn_s_sleep(1);
    }
    __threadfence();   // acquire: invalidate caches so we see others' writes
  }
  __syncthreads();
}

__global__ __launch_bounds__(256) void scan_k(SC s) {
  const int wg = blockIdx.x;
  const int v = threadIdx.x >> 6, l = threadIdx.x & 63, lm = l & 15, q = l >> 4;
  __shared__ float lds_ems[16 * 128];
  __shared__ u16   lds_z[16 * 64];

  for (int t = 0; t < TT; t++) {
    const u16* Ht = s.H + (size_t)t * (BB * HD);

    // ---- P1: A = relu(PRE_ENC[t] + h@enc_w1_h)   [wg 0..15,  cols 32wg]
    //          GH = h@gru_w_hh + b_hh              [wg 16..63, cols 32(wg-16)]
    {
      f32x4 acc[4][2] = {};
      const bool isA = (wg < 16);
      const int c0 = (isA ? wg : wg - 16) * 32;
      const u16* Bt = isA ? s.enc_w1_h_t : s.gru_hh_t;
      for (int k0 = 0; k0 < 512; k0 += 32) {
        bf16x8 b0 = *(const bf16x8*)(Bt + (size_t)(c0 + lm) * 512 + k0 + q * 8);
        bf16x8 b1 = *(const bf16x8*)(Bt + (size_t)(c0 + 16 + lm) * 512 + k0 + q * 8);
        #pragma unroll
        for (int rt = 0; rt < 4; rt++) {
          bf16x8 a = *(const bf16x8*)(Ht + (size_t)(v * 64 + rt * 16 + lm) * 512 + k0 + q * 8);
          acc[rt][0] = MFMA(a, b0, acc[rt][0]);
          acc[rt][1] = MFMA(a, b1, acc[rt][1]);
        }
      }
      if (isA) {
        const u16* pre = s.pre_enc + (size_t)t * (BB * HD);
        #pragma unroll
        for (int rt = 0; rt < 4; rt++)
          #pragma unroll
          for (int ct = 0; ct < 2; ct++)
            #pragma unroll
            for (int r = 0; r < 4; r++) {
              const int row = v * 64 + rt * 16 + q * 4 + r;
              const int col = c0 + ct * 16 + lm;
              const float x = acc[rt][ct][r] + bf2f(pre[(size_t)row * 512 + col]);
              s.A_buf[(size_t)row * 512 + col] = f2bf(fmaxf(x, 0.f));
            }
      } else {
        #pragma unroll
        for (int rt = 0; rt < 4; rt++)
          #pragma unroll
          for (int ct = 0; ct < 2; ct++)
            #pragma unroll
            for (int r = 0; r < 4; r++) {
              const int row = v * 64 + rt * 16 + q * 4 + r;
              const int col = c0 + ct * 16 + lm;
              s.GH[(size_t)row * 1536 + col] = acc[rt][ct][r] + s.gru_b_hh[col];
            }
      }
    }
    gridbar(s.flags, s.gen, (unsigned)(t * 4 + 1));

    // ---- P2: E = relu(A@enc_w2 + b2)             [wg 0..15]
    //          GXPX = px[t]@gru_w_ih_top + b_ih    [wg 16..63]
    {
      f32x4 acc[4][2] = {};
      const bool isE = (wg < 16);
      const int c0 = (isE ? wg : wg - 16) * 32;
      const u16* A = isE ? s.A_buf : (s.px + (size_t)t * (BB * HD));
      const u16* Bt = isE ? s.enc_w2_t : s.gru_ih_px_t;
      for (int k0 = 0; k0 < 512; k0 += 32) {
        bf16x8 b0 = *(const bf16x8*)(Bt + (size_t)(c0 + lm) * 512 + k0 + q * 8);
        bf16x8 b1 = *(const bf16x8*)(Bt + (size_t)(c0 + 16 + lm) * 512 + k0 + q * 8);
        #pragma unroll
        for (int rt = 0; rt < 4; rt++) {
          bf16x8 a = *(const bf16x8*)(A + (size_t)(v * 64 + rt * 16 + lm) * 512 + k0 + q * 8);
          acc[rt][0] = MFMA(a, b0, acc[rt][0]);
          acc[rt][1] = MFMA(a, b1, acc[rt][1]);
        }
      }
      if (isE) {
        #pragma unroll
        for (int rt = 0; rt < 4; rt++)
          #pragma unroll
          for (int ct = 0; ct < 2; ct++)
            #pragma unroll
            for (int r = 0; r < 4; r++) {
              const int row = v * 64 + rt * 16 + q * 4 + r;
              const int col = c0 + ct * 16 + lm;
              const float x = acc[rt][ct][r] + s.enc_b2[col];
              s.E_buf[(size_t)row * 512 + col] = f2bf(fmaxf(x, 0.f));
            }
      } else {
        #pragma unroll
        for (int rt = 0; rt < 4; rt++)
          #pragma unroll
          for (int ct = 0; ct < 2; ct++)
            #pragma unroll
            for (int r = 0; r < 4; r++) {
              const int row = v * 64 + rt * 16 + q * 4 + r;
              const int col = c0 + ct * 16 + lm;
              s.GXPX[(size_t)row * 1536 + col] = acc[rt][ct][r] + s.gru_b_ih[col];
            }
      }
    }
    gridbar(s.flags, s.gen, (unsigned)(t * 4 + 2));

    // ---- P3: per-WG 16 rows: EMS -> z (out) -> PZ.  [wg 0..15]
    if (wg < 16) {
      const int r0 = wg * 16;
      {
        f32x4 e0 = {}, e1 = {};
        const int cb = v * 32;
        for (int k0 = 0; k0 < 512; k0 += 32) {
          bf16x8 a  = *(const bf16x8*)(s.E_buf + (size_t)(r0 + lm) * 512 + k0 + q * 8);
          bf16x8 b0 = *(const bf16x8*)(s.ems_t + (size_t)(cb + lm) * 512 + k0 + q * 8);
          bf16x8 b1 = *(const bf16x8*)(s.ems_t + (size_t)(cb + 16 + lm) * 512 + k0 + q * 8);
          e0 = MFMA(a, b0, e0);
          e1 = MFMA(a, b1, e1);
        }
        #pragma unroll
        for (int ct = 0; ct < 2; ct++) {
          const int col = cb + ct * 16 + lm;
          const float bs = (col < 64) ? s.enc_mean_b[col] : s.enc_std_b[col - 64];
          const f32x4 ee = ct ? e1 : e0;
          #pragma unroll
          for (int r = 0; r < 4; r++)
            lds_ems[(q * 4 + r) * 128 + col] = ee[r] + bs;
        }
      }
      __syncthreads();
      #pragma unroll
      for (int i = 0; i < 4; i++) {
        const int e = threadIdx.x + i * 256;      // 16 rows x 64 cols
        const int rr = e >> 6, cc = e & 63;
        const float em = lds_ems[rr * 128 + cc];
        const float es = sp_(lds_ems[rr * 128 + 64 + cc]);
        const int row = r0 + rr;
        const size_t oi = ((size_t)t * BB + row) * 64 + cc;
        const float z = s.eps[oi] * es + em;
        s.out[OFF_Z + oi]  = z;
        s.out[OFF_EM + oi] = em;
        s.out[OFF_ES + oi] = es;
        lds_z[rr * 64 + cc] = f2bf(z);
      }
      __syncthreads();
      #pragma unroll
      for (int ct = 0; ct < 8; ct++) {
        const int cz = v * 128 + ct * 16;
        f32x4 pa = {};
        #pragma unroll
        for (int k0 = 0; k0 < 64; k0 += 32) {
          bf16x8 a = *(const bf16x8*)(lds_z + lm * 64 + k0 + q * 8);
          bf16x8 b = *(const bf16x8*)(s.phi_z_t + (size_t)(cz + lm) * 64 + k0 + q * 8);
          pa = MFMA(a, b, pa);
        }
        const int col = cz + lm;
        const float bs = s.phi_z_b[col];
        #pragma unroll
        for (int r = 0; r < 4; r++) {
          const int row = r0 + q * 4 + r;
          s.PZ_buf[(size_t)row * 512 + col] = f2bf(fmaxf(pa[r] + bs, 0.f));
        }
      }
    }
    gridbar(s.flags, s.gen, (unsigned)(t * 4 + 3));

    // ---- P4: gx = GXPX + pz@gru_w_ih_bot; GRU update  [wg 0..31, 16 h-cols each]
    if (wg < 32) {
      const int c0 = wg * 16;
      f32x4 acc[4][3] = {};
      for (int k0 = 0; k0 < 512; k0 += 32) {
        bf16x8 bg0 = *(const bf16x8*)(s.gru_ih_pz_t + (size_t)(c0 + lm) * 512 + k0 + q * 8);
        bf16x8 bg1 = *(const bf16x8*)(s.gru_ih_pz_t + (size_t)(512 + c0 + lm) * 512 + k0 + q * 8);
        bf16x8 bg2 = *(const bf16x8*)(s.gru_ih_pz_t + (size_t)(1024 + c0 + lm) * 512 + k0 + q * 8);
        #pragma unroll
        for (int rt = 0; rt < 4; rt++) {
          bf16x8 a = *(const bf16x8*)(s.PZ_buf + (size_t)(v * 64 + rt * 16 + lm) * 512 + k0 + q * 8);
          acc[rt][0] = MFMA(a, bg0, acc[rt][0]);
          acc[rt][1] = MFMA(a, bg1, acc[rt][1]);
          acc[rt][2] = MFMA(a, bg2, acc[rt][2]);
        }
      }
      const int j = c0 + lm;
      #pragma unroll
      for (int rt = 0; rt < 4; rt++)
        #pragma unroll
        for (int r = 0; r < 4; r++) {
          const int row = v * 64 + rt * 16 + q * 4 + r;
          const size_t rb = (size_t)row * 1536;
          const float xr = acc[rt][0][r] + s.GXPX[rb + j];
          const float xz = acc[rt][1][r] + s.GXPX[rb + 512 + j];
          const float xn = acc[rt][2][r] + s.GXPX[rb + 1024 + j];
          const float hr = s.GH[rb + j];
          const float hz = s.GH[rb + 512 + j];
          const float hn = s.GH[rb + 1024 + j];
          const float rg = sigm_(xr + hr);
          const float uu = sigm_(xz + hz);
          const float nn = tanhf(xn + rg * hn);
          const float hold = s.h_cur[(size_t)row * 512 + j];
          const float hnew = (1.f - uu) * nn + uu * hold;
          s.h_cur[(size_t)row * 512 + j] = hnew;
          if (t < TT - 1)
            s.H[(size_t)(t + 1) * (BB * HD) + (size_t)row * 512 + j] = f2bf(hnew);
        }
    }
    gridbar(s.flags, s.gen, (unsigned)(t * 4 + 4));
  }
}

// ---------------------------------------------------------------------------
extern "C" void kernel_launch(void* const* d_in, const int* in_sizes, int n_in,
                              void* d_out, int out_size, void* d_ws, size_t ws_size,
                              hipStream_t stream) {
  (void)in_sizes; (void)n_in; (void)out_size; (void)ws_size;
  char* ws = (char*)d_ws;
  float* out = (float*)d_out;
  auto in = [&](int i) { return (const float*)d_in[i]; };

  size_t o = 0;
  auto take = [&](size_t bytes) { size_t r = o; o += (bytes + 255) & ~(size_t)255; return r; };
  const size_t oPhiXW1  = take(512 * 128 * 2);
  const size_t oPhiXW2  = take(512 * 512 * 2);
  const size_t oEncW1px = take(512 * 512 * 2);
  const size_t oEncW1h  = take(512 * 512 * 2);
  const size_t oEncW2   = take(512 * 512 * 2);
  const size_t oEms     = take(128 * 512 * 2);
  const size_t oPhiZ    = take(512 * 64 * 2);
  const size_t oPriorW  = take(512 * 512 * 2);
  const size_t oPriorMs = take(128 * 512 * 2);
  const size_t oDecW1pz = take(512 * 512 * 2);
  const size_t oDecW1h  = take(512 * 512 * 2);
  const size_t oDecW2   = take(512 * 512 * 2);
  const size_t oDecLog  = take(256 * 512 * 2);
  const size_t oGruIhPx = take((size_t)1536 * 512 * 2);
  const size_t oGruIhPz = take((size_t)1536 * 512 * 2);
  const size_t oGruHh   = take((size_t)1536 * 512 * 2);
  const size_t oBuf0    = take((size_t)TB * 512 * 2);
  const size_t oBuf1    = take((size_t)TB * 512 * 2);
  const size_t oH       = take((size_t)TB * 512 * 2);
  const size_t oHcur    = take((size_t)BB * 512 * 4);
  const size_t oAbuf    = take((size_t)BB * 512 * 2);
  const size_t oEbuf    = take((size_t)BB * 512 * 2);
  const size_t oPZbuf   = take((size_t)BB * 512 * 2);
  const size_t oGH      = take((size_t)BB * 1536 * 4);
  const size_t oGXPX    = take((size_t)BB * 1536 * 4);
  const size_t oSync    = take(16384);

  auto W = [&](size_t off) { return (u16*)(ws + off); };
  u16* BUF0 = W(oBuf0);
  u16* BUF1 = W(oBuf1);
  u16* Hbuf = W(oH);
  float* h_cur = (float*)(ws + oHcur);
  unsigned* sync = (unsigned*)(ws + oSync);

  // --- weight cast+transpose (one kernel, 18 segments) ---
  CastArgs ca;
  int si = 0;
  auto seg = [&](const float* src, u16* dst, int R, int C) { ca.seg[si++] = {src, dst, R, C}; };
  seg(in(2), W(oPhiXW1), 128, 512);
  seg(in(4), W(oPhiXW2), 512, 512);
  seg(in(8), W(oEncW1px), 512, 512);
  seg(in(8) + 512 * 512, W(oEncW1h), 512, 512);
  seg(in(10), W(oEncW2), 512, 512);
  seg(in(12), W(oEms), 512, 64);
  seg(in(14), W(oEms) + 64 * 512, 512, 64);
  seg(in(6), W(oPhiZ), 64, 512);
  seg(in(16), W(oPriorW), 512, 512);
  seg(in(18), W(oPriorMs), 512, 64);
  seg(in(20), W(oPriorMs) + 64 * 512, 512, 64);
  seg(in(22), W(oDecW1pz), 512, 512);
  seg(in(22) + 512 * 512, W(oDecW1h), 512, 512);
  seg(in(24), W(oDecW2), 512, 512);
  seg(in(26), W(oDecLog), 512, 256);
  seg(in(28), W(oGruIhPx), 512, 1536);
  seg(in(28) + 512 * 1536, W(oGruIhPz), 512, 1536);
  seg(in(30), W(oGruHh), 512, 1536);
  hipLaunchKernelGGL(cast_all, dim3(18816), dim3(256), 0, stream, ca);
  hipLaunchKernelGGL(init_k, dim3(512), dim3(256), 0, stream, h_cur, Hbuf, sync);

  auto gemm = [&](const void* A1, int lda1, int K1, int a1f32, const u16* Bt1,
                  const u16* A2, int lda2, int K2, const u16* Bt2,
                  const float* bias, u16* outB, float* outF, int ldc, int N, int act) {
    GB g;
    g.A1 = A1; g.lda1 = lda1; g.K1 = K1; g.a1f32 = a1f32; g.Bt1 = Bt1;
    g.A2 = A2; g.lda2 = lda2; g.K2 = K2; g.Bt2 = Bt2;
    g.bias = bias; g.outB = outB; g.outF = outF; g.ldc = ldc;
    g.tilesN = N / 64; g.act = act;
    hipLaunchKernelGGL(gemm_bt, dim3((TB / 64) * (N / 64)), dim3(256), 0, stream, g);
  };

  // --- pre-pass ---
  // PX1 = relu(x @ phi_x_w1 + b1)          -> BUF0
  gemm(in(0), 128, 128, 1, W(oPhiXW1), nullptr, 0, 0, nullptr, in(3), BUF0, nullptr, 512, 512, 1);
  // PX  = relu(PX1 @ phi_x_w2 + b2)        -> BUF1
  gemm(BUF0, 512, 512, 0, W(oPhiXW2), nullptr, 0, 0, nullptr, in(5), BUF1, nullptr, 512, 512, 1);
  // PRE_ENC = PX @ enc_w1[:512] + enc_b1   -> BUF0
  gemm(BUF1, 512, 512, 0, W(oEncW1px), nullptr, 0, 0, nullptr, in(9), BUF0, nullptr, 512, 512, 0);

  // --- sequential scan ---
  SC sc;
  sc.pre_enc = BUF0; sc.px = BUF1;
  sc.H = Hbuf; sc.h_cur = h_cur;
  sc.A_buf = W(oAbuf); sc.E_buf = W(oEbuf); sc.PZ_buf = W(oPZbuf);
  sc.GH = (float*)(ws + oGH); sc.GXPX = (float*)(ws + oGXPX);
  sc.enc_w1_h_t = W(oEncW1h); sc.enc_w2_t = W(oEncW2); sc.ems_t = W(oEms);
  sc.phi_z_t = W(oPhiZ); sc.gru_hh_t = W(oGruHh);
  sc.gru_ih_pz_t = W(oGruIhPz); sc.gru_ih_px_t = W(oGruIhPx);
  sc.enc_b2 = in(11); sc.enc_mean_b = in(13); sc.enc_std_b = in(15);
  sc.phi_z_b = in(7); sc.gru_b_ih = in(29); sc.gru_b_hh = in(31);
  sc.eps = in(1); sc.out = out;
  sc.flags = sync; sc.gen = sync + 2048;
  hipLaunchKernelGGL(scan_k, dim3(NWG), dim3(256), 0, stream, sc);

  // --- post-pass (batched over all T) ---
  // PZ = relu(z @ phi_z + b)               -> BUF0  (z read fp32 from d_out)
  gemm(out + OFF_Z, 64, 64, 1, W(oPhiZ), nullptr, 0, 0, nullptr, in(7), BUF0, nullptr, 512, 512, 1);
  // PR = relu(Hprev @ prior_w + b)         -> BUF1
  gemm(Hbuf, 512, 512, 0, W(oPriorW), nullptr, 0, 0, nullptr, in(17), BUF1, nullptr, 512, 512, 1);
  // pm/ps/kld                              -> d_out
  hipLaunchKernelGGL(pms_kld, dim3(TB / 64), dim3(256), 0, stream,
                     BUF1, W(oPriorMs), in(19), in(21), out);
  // DH1 = relu(PZ@dec_w1[:512] + Hprev@dec_w1[512:] + b1) -> BUF1
  gemm(BUF0, 512, 512, 0, W(oDecW1pz), Hbuf, 512, 512, W(oDecW1h), in(23), BUF1, nullptr, 512, 512, 1);
  // D = relu(DH1 @ dec_w2 + b2)            -> BUF0
  gemm(BUF1, 512, 512, 0, W(oDecW2), nullptr, 0, 0, nullptr, in(25), BUF0, nullptr, 512, 512, 1);
  // logits = D @ dec_logits + b            -> d_out fp32
  gemm(BUF0, 512, 512, 0, W(oDecLog), nullptr, 0, 0, nullptr, in(27), nullptr, out + OFF_LOGITS, 256, 256, 0);
}